// Round 7
// baseline (2771.473 us; speedup 1.0000x reference)
//
#include <hip/hip_runtime.h>

namespace {

typedef _Float16 h2 __attribute__((ext_vector_type(2)));

constexpr int KSTEPS = 512;
constexpr int NSTATE = 128;
constexpr int NINPUT = 32;
constexpr int HID    = 256;
constexpr int FANIN  = 161;

// z (f16): [y 0..127 | u 128..159 | t 160 | zero pad 161..191]
constexpr int ZST = 192;
// h: 16 chunks, stride 24 f16 (16 valid + 8 pad). 48 B stride -> 16B-aligned b128,
// banks 12k%32: 2-way alias only (free). Row j at hs[24*(j>>4) + (j&15)].
constexpr int HCH = 24;
constexpr int HST = 16 * HCH;   // 384

__device__ __forceinline__ float fdot2(h2 a, h2 b, float c) {
#if __has_builtin(__builtin_amdgcn_fdot2)
  return __builtin_amdgcn_fdot2(a, b, c, false);
#else
  return c + (float)a[0] * (float)b[0] + (float)a[1] * (float)b[1];
#endif
}

__device__ __forceinline__ float fast_tanh(float x) {
  float e2 = __expf(2.0f * x);
  return 1.0f - 2.0f / (e2 + 1.0f);
}

template <int CTRL>
__device__ __forceinline__ float dpp_add(float x) {
  int y = __builtin_amdgcn_update_dpp(0, __float_as_int(x), CTRL, 0xF, 0xF, false);
  return x + __int_as_float(y);
}
// sum across 8 consecutive lanes
__device__ __forceinline__ float red8(float x) {
  x = dpp_add<0xB1>(x);    // xor 1
  x = dpp_add<0x4E>(x);    // xor 2
  x = dpp_add<0x141>(x);   // half-row mirror
  return x;
}
// sum across 16 consecutive lanes
__device__ __forceinline__ float red16(float x) {
  x = dpp_add<0xB1>(x);
  x = dpp_add<0x4E>(x);
  x = dpp_add<0x141>(x);
  x = dpp_add<0x140>(x);   // row mirror
  return x;
}

// Barrier with LDS-only drain (skip vmcnt(0): out-stores / us-loads stay in flight).
#define BAR() __asm__ volatile("s_waitcnt lgkmcnt(0)\n\ts_barrier" ::: "memory")

union F4 { float4 f; h2 h[4]; };

// 64 blocks x 512 threads, one trajectory per block (8 waves = 2/SIMD, 64 CUs).
// Layer1 (S=8): thread (g=lt>>3 in 0..63, kc8=lt&7): rows 4g..4g+3 x z-chunk kc8 (24 f16).
// Layer2 (S=16): thread (g2=lt>>4 in 0..31, kc16=lt&15): rows 4g2..4g2+3 x h-chunk kc16 (16 f16).
// Reductions: DPP butterflies (red8 / red16). 2 lgkm-only barriers per stage.
__global__ __launch_bounds__(512, 2)
void ode_tsit5_kernel(const float* __restrict__ ts,
                      const float* __restrict__ y0,
                      const float* __restrict__ us,
                      const float* __restrict__ W1,
                      const float* __restrict__ b1,
                      const float* __restrict__ W2,
                      const float* __restrict__ b2,
                      float* __restrict__ out)
{
  const int lt   = threadIdx.x;        // 0..511
  const int g    = lt >> 3;            // 0..63  (layer1)
  const int kc8  = lt & 7;             // 0..7   (layer1 k-chunk)
  const int g2   = lt >> 4;            // 0..31  (layer2)
  const int kc16 = lt & 15;            // 0..15  (layer2 k-chunk)
  const int b    = blockIdx.x;

  __shared__ __align__(16) _Float16 z16[ZST];
  __shared__ __align__(16) _Float16 hs[HST];

  // ---- pack weights into f16-pair registers ----
  // z position p -> W1 column: p<160 -> p+1 (y,u), p==160 -> 0 (t), else 0 (pad).
  h2 w1[4][12];
  #pragma unroll
  for (int r = 0; r < 4; ++r) {
    const float* row = W1 + (long)(4 * g + r) * FANIN;
    #pragma unroll
    for (int i = 0; i < 12; ++i) {
      const int p0 = 24 * kc8 + 2 * i;
      const int p1 = p0 + 1;
      const float f0 = (p0 < 160) ? row[p0 + 1] : ((p0 == 160) ? row[0] : 0.0f);
      const float f1 = (p1 < 160) ? row[p1 + 1] : ((p1 == 160) ? row[0] : 0.0f);
      w1[r][i] = h2{(_Float16)f0, (_Float16)f1};
    }
  }
  h2 w2[4][8];
  #pragma unroll
  for (int r = 0; r < 4; ++r) {
    const float* row = W2 + (long)(4 * g2 + r) * HID + 16 * kc16;
    #pragma unroll
    for (int i = 0; i < 8; ++i)
      w2[r][i] = h2{(_Float16)row[2 * i], (_Float16)row[2 * i + 1]};
  }

  const int   jrow = 4 * g + kc8;                     // layer1 store row (kc8<4)
  const float b1r  = (kc8 < 4) ? b1[jrow] : 0.0f;
  const int   hidx = (kc8 < 4) ? (HCH * (jrow >> 4) + (jrow & 15)) : 0;
  const int   orow = 4 * g2 + kc16;                   // layer2/combine row (kc16<4)
  const float b2r  = (kc16 < 4) ? b2[orow] : 0.0f;

  // Tsit5 tableau (b7 = 0 path)
  constexpr float Cc[5] = {0.161f, 0.327f, 0.9f, 0.9800255409045097f, 1.0f};
  constexpr double CcD[5] = {0.161, 0.327, 0.9, 0.9800255409045097, 1.0};
  constexpr float Af[5][5] = {
    {0.161f, 0.f, 0.f, 0.f, 0.f},
    {-0.008480655492356989f, 0.335480655492357f, 0.f, 0.f, 0.f},
    {2.8971530571054935f, -6.359448489975075f, 4.3622954328695815f, 0.f, 0.f},
    {5.325864828439257f, -11.748883564062828f, 7.4955393428898365f, -0.09249506636175525f, 0.f},
    {5.86145544294642f, -12.92096931784711f, 8.159367898576159f, -0.071584973281401f,
     -0.028269050394068383f}};
  constexpr float Bf[6] = {0.09646076681806523f, 0.01f, 0.4798896504144996f,
                           1.379008574103742f, -3.290069515436081f, 2.324710524099774f};

  // ---- init ----
  float yR = 0.0f, ksR[6] = {0.f, 0.f, 0.f, 0.f, 0.f, 0.f};
  if (kc16 < 4) {
    yR = y0[(long)b * NSTATE + orow];
    z16[orow] = (_Float16)yR;
    out[(long)b * KSTEPS * NSTATE + orow] = yR;
  }
  if (lt < ZST - FANIN) z16[FANIN + lt] = (_Float16)0.0f;  // pad, never rewritten

  const bool is_u = (kc8 == 4) && (g < 32);   // kc16 in {4,12}: disjoint from combine/t lanes
  const int  m    = g & 31;
  const float* usb = us + (long)b * KSTEPS * NINPUT;
  float u0v = 0.f, u1v = 0.f, u2v = 0.f, uprev = 0.f;
  if (is_u) {
    u0v = usb[m];
    u1v = usb[NINPUT + m];
    z16[128 + m] = (_Float16)u0v;
  }
  float tcur = ts[0], tn1 = ts[1];
  float dtp  = 1.0f;
  if (lt == 5) z16[160] = (_Float16)tcur;

  for (int i = 0; i < KSTEPS - 1; ++i) {
    const float dt = tn1 - tcur;
    const int   i2 = (i + 2 < KSTEPS) ? (i + 2) : (KSTEPS - 1);
    const float tn2 = ts[i2];                       // prefetch for next step
    if (is_u) u2v = usb[(long)i2 * NINPUT + m];     // prefetch for next step

    float hd0v = 0.f;
    if (is_u) hd0v = (i == 0) ? (u1v - u0v) : (u0v - uprev) * (dt / dtp);

    #pragma unroll
    for (int e = 0; e < 6; ++e) {
      BAR();   // z16 ready

      // ---- layer 1: 4 rows x 24-f16 z chunk, 2 chains per row ----
      const F4* zp = (const F4*)(&z16[24 * kc8]);
      F4 zc0 = zp[0], zc1 = zp[1], zc2 = zp[2];
      float acc[4];
      #pragma unroll
      for (int r = 0; r < 4; ++r) {
        float a0 = fdot2(w1[r][0], zc0.h[0], 0.0f);
        float a1 = fdot2(w1[r][1], zc0.h[1], 0.0f);
        a0 = fdot2(w1[r][2],  zc0.h[2], a0);
        a1 = fdot2(w1[r][3],  zc0.h[3], a1);
        a0 = fdot2(w1[r][4],  zc1.h[0], a0);
        a1 = fdot2(w1[r][5],  zc1.h[1], a1);
        a0 = fdot2(w1[r][6],  zc1.h[2], a0);
        a1 = fdot2(w1[r][7],  zc1.h[3], a1);
        a0 = fdot2(w1[r][8],  zc2.h[0], a0);
        a1 = fdot2(w1[r][9],  zc2.h[1], a1);
        a0 = fdot2(w1[r][10], zc2.h[2], a0);
        a1 = fdot2(w1[r][11], zc2.h[3], a1);
        acc[r] = a0 + a1;
      }
      #pragma unroll
      for (int r = 0; r < 4; ++r) acc[r] = red8(acc[r]);
      float sel = acc[0];
      #pragma unroll
      for (int r = 1; r < 4; ++r) sel = (kc8 == r) ? acc[r] : sel;
      if (kc8 < 4) hs[hidx] = (_Float16)fast_tanh(b1r + sel);

      BAR();   // hs ready

      // ---- phase-2 head: issue h reads, then hoisted u/t writes (indep of L2) ----
      const F4* hp4 = (const F4*)(&hs[HCH * kc16]);
      F4 hc0 = hp4[0], hc1 = hp4[1];

      if (e < 5) {
        if (is_u) {
          const double th = CcD[e];
          const float cu0 = (float)(th * th * th - 2.0 * th * th + 1.0);
          const float cu1 = (float)(2.0 * th * th - th * th * th);
          const float cd0 = (float)(th * th * th - 2.0 * th * th + th);
          z16[128 + m] = (_Float16)(cu0 * u0v + cu1 * u1v + cd0 * hd0v);
        }
        if (lt == 5) z16[160] = (_Float16)__builtin_fmaf(Cc[e], dt, tcur);
      } else {
        if (is_u) z16[128 + m] = (_Float16)u1v;   // theta=0 of next step
        if (lt == 5) z16[160] = (_Float16)tn1;
      }

      // ---- layer 2: 4 rows x 16-f16 h chunk, 2 chains per row ----
      float a2[4];
      #pragma unroll
      for (int r = 0; r < 4; ++r) {
        float c0 = fdot2(w2[r][0], hc0.h[0], 0.0f);
        float c1 = fdot2(w2[r][1], hc0.h[1], 0.0f);
        c0 = fdot2(w2[r][2], hc0.h[2], c0);
        c1 = fdot2(w2[r][3], hc0.h[3], c1);
        c0 = fdot2(w2[r][4], hc1.h[0], c0);
        c1 = fdot2(w2[r][5], hc1.h[1], c1);
        c0 = fdot2(w2[r][6], hc1.h[2], c0);
        c1 = fdot2(w2[r][7], hc1.h[3], c1);
        a2[r] = c0 + c1;
      }
      #pragma unroll
      for (int r = 0; r < 4; ++r) a2[r] = red16(a2[r]);
      float sel2 = a2[0];
      #pragma unroll
      for (int r = 1; r < 4; ++r) sel2 = (kc16 == r) ? a2[r] : sel2;

      // ---- tableau combine on kc16<4 lanes ----
      if (kc16 < 4) {
        ksR[e] = b2r + sel2;
        if (e < 5) {
          float acm = 0.f;
          #pragma unroll
          for (int mm = 0; mm <= e; ++mm) acm = __builtin_fmaf(Af[e][mm], ksR[mm], acm);
          z16[orow] = (_Float16)__builtin_fmaf(dt, acm, yR);
        } else {
          float acm = 0.f;
          #pragma unroll
          for (int mm = 0; mm < 6; ++mm) acm = __builtin_fmaf(Bf[mm], ksR[mm], acm);
          yR = __builtin_fmaf(dt, acm, yR);
          z16[orow] = (_Float16)yR;
          out[((long)b * KSTEPS + (i + 1)) * NSTATE + orow] = yR;
        }
      }
    }

    if (is_u) { uprev = u0v; u0v = u1v; u1v = u2v; }
    dtp  = dt;
    tcur = tn1;
    tn1  = tn2;
  }
}

} // namespace

extern "C" void kernel_launch(void* const* d_in, const int* in_sizes, int n_in,
                              void* d_out, int out_size, void* d_ws, size_t ws_size,
                              hipStream_t stream) {
  const float* ts = (const float*)d_in[0];
  const float* y0 = (const float*)d_in[1];
  const float* us = (const float*)d_in[2];
  const float* W1 = (const float*)d_in[3];
  const float* b1 = (const float*)d_in[4];
  const float* W2 = (const float*)d_in[5];
  const float* b2 = (const float*)d_in[6];
  float* out = (float*)d_out;
  hipLaunchKernelGGL(ode_tsit5_kernel, dim3(64), dim3(512), 0, stream,
                     ts, y0, us, W1, b1, W2, b2, out);
}

// Round 8
// 2272.544 us; speedup vs baseline: 1.2195x; 1.2195x over previous
//
#include <hip/hip_runtime.h>

namespace {

typedef _Float16 h2 __attribute__((ext_vector_type(2)));

constexpr int KSTEPS = 512;
constexpr int NSTATE = 128;
constexpr int NINPUT = 32;
constexpr int HID    = 256;
constexpr int FANIN  = 161;

// z (f16): [y 0..127 | u 128..159]  (t handled per-owner-lane in registers)
constexpr int ZST = 160;
// h: 8 chunks, stride 40 f16 (32 valid + 8 pad), conflict-free b128 reads
constexpr int HCH = 40;
constexpr int HST = 8 * HCH;   // 320

__device__ __forceinline__ float fdot2(h2 a, h2 b, float c) {
#if __has_builtin(__builtin_amdgcn_fdot2)
  return __builtin_amdgcn_fdot2(a, b, c, false);
#else
  return c + (float)a[0] * (float)b[0] + (float)a[1] * (float)b[1];
#endif
}

__device__ __forceinline__ float fast_tanh(float x) {
  float e2 = __expf(2.0f * x);
  return 1.0f - 2.0f / (e2 + 1.0f);
}

template <int CTRL>
__device__ __forceinline__ float dpp_add(float x) {
  int y = __builtin_amdgcn_update_dpp(0, __float_as_int(x), CTRL, 0xF, 0xF, false);
  return x + __int_as_float(y);
}
// sum across 8 consecutive lanes (3-step DPP butterfly, VALU pipe only)
__device__ __forceinline__ float red8(float x) {
  x = dpp_add<0xB1>(x);    // xor 1
  x = dpp_add<0x4E>(x);    // xor 2
  x = dpp_add<0x141>(x);   // half-row mirror
  return x;
}

// Barrier with LDS-only drain: skip the vmcnt(0) drain __syncthreads() forces,
// so global out-stores / us-loads stay in flight across stage boundaries.
#define BAR() __asm__ volatile("s_waitcnt lgkmcnt(0)\n\ts_barrier" ::: "memory")

union F4 { float4 f; h2 h[4]; };
union F2 { float2 f; h2 h[2]; };

// 64 blocks x 256 threads, one trajectory per block (4 waves, 1 wave/SIMD).
// Thread (g=lt>>3 in 0..31, kc=lt&7):
//   Layer1: hidden rows 8g..8g+7; y-chunk = 16 f16 at 16kc (2x b128), u-chunk =
//           4 f16 at 128+4kc (1x b64); t applied per-owner-lane (w1t * t_e).
//   Layer2: state rows 4g..4g+3 x h-chunk kc (32 f16, stride-40 padded).
// Reductions: 3-step DPP butterfly over the 8 kc lanes. 2 lgkm-only barriers/stage.
__global__ __launch_bounds__(256, 1)
void ode_tsit5_kernel(const float* __restrict__ ts,
                      const float* __restrict__ y0,
                      const float* __restrict__ us,
                      const float* __restrict__ W1,
                      const float* __restrict__ b1,
                      const float* __restrict__ W2,
                      const float* __restrict__ b2,
                      float* __restrict__ out)
{
  const int lt = threadIdx.x;          // 0..255
  const int g  = lt >> 3;              // 0..31
  const int kc = lt & 7;               // 0..7
  const int b  = blockIdx.x;

  __shared__ __align__(16) _Float16 z16[ZST];
  __shared__ __align__(16) _Float16 hs[HST];

  // ---- pack weights into f16-pair registers ----
  // W1 cols: [0]=t, [1..128]=y, [129..160]=u.  z pos p -> col p+1.
  h2 w1y[8][8];
  h2 w1u[8][2];
  #pragma unroll
  for (int r = 0; r < 8; ++r) {
    const float* row = W1 + (long)(8 * g + r) * FANIN;
    #pragma unroll
    for (int i = 0; i < 8; ++i) {
      const int c = 16 * kc + 2 * i + 1;              // y cols
      w1y[r][i] = h2{(_Float16)row[c], (_Float16)row[c + 1]};
    }
    #pragma unroll
    for (int i = 0; i < 2; ++i) {
      const int c = 129 + 4 * kc + 2 * i;             // u cols
      w1u[r][i] = h2{(_Float16)row[c], (_Float16)row[c + 1]};
    }
  }
  h2 w2[4][16];
  #pragma unroll
  for (int r = 0; r < 4; ++r) {
    const float* row = W2 + (long)(4 * g + r) * HID + 32 * kc;
    #pragma unroll
    for (int i = 0; i < 16; ++i)
      w2[r][i] = h2{(_Float16)row[2 * i], (_Float16)row[2 * i + 1]};
  }

  const int   jrow = 8 * g + kc;                      // layer1 owner row (all kc)
  const float b1r  = b1[jrow];
  const float w1t  = W1[(long)jrow * FANIN];          // t column, fp32
  const int   hidx = HCH * (jrow >> 5) + (jrow & 31);
  const int   orow = 4 * g + kc;                      // layer2 row (kc<4)
  const float b2r  = (kc < 4) ? b2[orow] : 0.0f;

  // Tsit5 tableau (b7 = 0 path); TH[e] = stage abscissa (theta) for stage e.
  constexpr float TH[6] = {0.0f, 0.161f, 0.327f, 0.9f, 0.9800255409045097f, 1.0f};
  constexpr double CcD[5] = {0.161, 0.327, 0.9, 0.9800255409045097, 1.0};
  constexpr float Af[5][5] = {
    {0.161f, 0.f, 0.f, 0.f, 0.f},
    {-0.008480655492356989f, 0.335480655492357f, 0.f, 0.f, 0.f},
    {2.8971530571054935f, -6.359448489975075f, 4.3622954328695815f, 0.f, 0.f},
    {5.325864828439257f, -11.748883564062828f, 7.4955393428898365f, -0.09249506636175525f, 0.f},
    {5.86145544294642f, -12.92096931784711f, 8.159367898576159f, -0.071584973281401f,
     -0.028269050394068383f}};
  constexpr float Bf[6] = {0.09646076681806523f, 0.01f, 0.4798896504144996f,
                           1.379008574103742f, -3.290069515436081f, 2.324710524099774f};

  // ---- init ----
  float yR = 0.0f, ksR[6] = {0.f, 0.f, 0.f, 0.f, 0.f, 0.f};
  if (kc < 4) {
    yR = y0[(long)b * NSTATE + orow];
    z16[orow] = (_Float16)yR;
    out[(long)b * KSTEPS * NSTATE + orow] = yR;
  }

  const bool is_u = (kc == 4);
  const int  m    = g;                    // u component for kc==4 lanes (g<32 always)
  const float* usb = us + (long)b * KSTEPS * NINPUT;
  float u0v = 0.f, u1v = 0.f, u2v = 0.f, uprev = 0.f;
  if (is_u) {
    u0v = usb[m];
    u1v = usb[NINPUT + m];
    z16[128 + m] = (_Float16)u0v;
  }
  float tcur = ts[0], tn1 = ts[1];
  float dtp  = 1.0f;

  for (int i = 0; i < KSTEPS - 1; ++i) {
    const float dt = tn1 - tcur;
    const int   i2 = (i + 2 < KSTEPS) ? (i + 2) : (KSTEPS - 1);
    const float tn2 = ts[i2];                       // prefetch for next step
    if (is_u) u2v = usb[(long)i2 * NINPUT + m];     // prefetch for next step

    float hd0v = 0.f;
    if (is_u) hd0v = (i == 0) ? (u1v - u0v) : (u0v - uprev) * (dt / dtp);

    #pragma unroll
    for (int e = 0; e < 6; ++e) {
      BAR();   // z16 ready (LDS-only drain)

      const float te = __builtin_fmaf(TH[e], dt, tcur);

      // ---- layer 1: 8 rows x (16 y + 4 u) f16 chunk, 2 chains per row ----
      const F4* zp = (const F4*)(&z16[16 * kc]);
      F4 za = zp[0], zb = zp[1];
      F2 zu = *(const F2*)(&z16[128 + 4 * kc]);
      float acc[8];
      #pragma unroll
      for (int r = 0; r < 8; ++r) {
        float a0 = fdot2(w1y[r][0], za.h[0], 0.0f);
        float a1 = fdot2(w1y[r][1], za.h[1], 0.0f);
        a0 = fdot2(w1y[r][2], za.h[2], a0);
        a1 = fdot2(w1y[r][3], za.h[3], a1);
        a0 = fdot2(w1y[r][4], zb.h[0], a0);
        a1 = fdot2(w1y[r][5], zb.h[1], a1);
        a0 = fdot2(w1y[r][6], zb.h[2], a0);
        a1 = fdot2(w1y[r][7], zb.h[3], a1);
        a0 = fdot2(w1u[r][0], zu.h[0], a0);
        a1 = fdot2(w1u[r][1], zu.h[1], a1);
        acc[r] = a0 + a1;
      }
      #pragma unroll
      for (int r = 0; r < 8; ++r) acc[r] = red8(acc[r]);
      float sel = acc[0];
      #pragma unroll
      for (int r = 1; r < 8; ++r) sel = (kc == r) ? acc[r] : sel;
      // owner row = 8g+kc; add bias + t-column contribution here (t left out of LDS)
      hs[hidx] = (_Float16)fast_tanh(__builtin_fmaf(w1t, te, b1r + sel));

      BAR();   // hs ready

      // ---- phase-2 head: issue h reads; hoisted u-write + combine base (indep of L2) ----
      const F4* hp4 = (const F4*)(&hs[HCH * kc]);
      F4 hc0 = hp4[0], hc1 = hp4[1], hc2 = hp4[2], hc3 = hp4[3];

      if (e < 5) {
        if (is_u) {
          const double th = CcD[e];     // theta of stage e+1
          const float cu0 = (float)(th * th * th - 2.0 * th * th + 1.0);
          const float cu1 = (float)(2.0 * th * th - th * th * th);
          const float cd0 = (float)(th * th * th - 2.0 * th * th + th);
          z16[128 + m] = (_Float16)(cu0 * u0v + cu1 * u1v + cd0 * hd0v);
        }
      } else {
        if (is_u) z16[128 + m] = (_Float16)u1v;   // theta=0 of next step
      }

      float base = yR;   // combine base: only terms m<e (already known)
      if (kc < 4) {
        if (e < 5) {
          float acm = 0.f;
          #pragma unroll
          for (int mm = 0; mm < e; ++mm) acm = __builtin_fmaf(Af[e][mm], ksR[mm], acm);
          base = __builtin_fmaf(dt, acm, yR);
        } else {
          float acm = 0.f;
          #pragma unroll
          for (int mm = 0; mm < 5; ++mm) acm = __builtin_fmaf(Bf[mm], ksR[mm], acm);
          base = __builtin_fmaf(dt, acm, yR);
        }
      }

      // ---- layer 2: 4 rows x 32-f16 h chunk, 2 chains per row ----
      float a2[4];
      #pragma unroll
      for (int r = 0; r < 4; ++r) {
        float c0 = fdot2(w2[r][0], hc0.h[0], 0.0f);
        float c1 = fdot2(w2[r][1], hc0.h[1], 0.0f);
        c0 = fdot2(w2[r][2],  hc0.h[2], c0);
        c1 = fdot2(w2[r][3],  hc0.h[3], c1);
        c0 = fdot2(w2[r][4],  hc1.h[0], c0);
        c1 = fdot2(w2[r][5],  hc1.h[1], c1);
        c0 = fdot2(w2[r][6],  hc1.h[2], c0);
        c1 = fdot2(w2[r][7],  hc1.h[3], c1);
        c0 = fdot2(w2[r][8],  hc2.h[0], c0);
        c1 = fdot2(w2[r][9],  hc2.h[1], c1);
        c0 = fdot2(w2[r][10], hc2.h[2], c0);
        c1 = fdot2(w2[r][11], hc2.h[3], c1);
        c0 = fdot2(w2[r][12], hc3.h[0], c0);
        c1 = fdot2(w2[r][13], hc3.h[1], c1);
        c0 = fdot2(w2[r][14], hc3.h[2], c0);
        c1 = fdot2(w2[r][15], hc3.h[3], c1);
        a2[r] = c0 + c1;
      }
      #pragma unroll
      for (int r = 0; r < 4; ++r) a2[r] = red8(a2[r]);
      float sel2 = a2[0];
      #pragma unroll
      for (int r = 1; r < 4; ++r) sel2 = (kc == r) ? a2[r] : sel2;

      // ---- short tail: 1 FMA + cvt + write ----
      if (kc < 4) {
        const float ke = b2r + sel2;
        ksR[e] = ke;
        if (e < 5) {
          z16[orow] = (_Float16)__builtin_fmaf(dt * Af[e][e], ke, base);
        } else {
          yR = __builtin_fmaf(dt * Bf[5], ke, base);
          z16[orow] = (_Float16)yR;
          out[((long)b * KSTEPS + (i + 1)) * NSTATE + orow] = yR;
        }
      }
    }

    if (is_u) { uprev = u0v; u0v = u1v; u1v = u2v; }
    dtp  = dt;
    tcur = tn1;
    tn1  = tn2;
  }
}

} // namespace

extern "C" void kernel_launch(void* const* d_in, const int* in_sizes, int n_in,
                              void* d_out, int out_size, void* d_ws, size_t ws_size,
                              hipStream_t stream) {
  const float* ts = (const float*)d_in[0];
  const float* y0 = (const float*)d_in[1];
  const float* us = (const float*)d_in[2];
  const float* W1 = (const float*)d_in[3];
  const float* b1 = (const float*)d_in[4];
  const float* W2 = (const float*)d_in[5];
  const float* b2 = (const float*)d_in[6];
  float* out = (float*)d_out;
  hipLaunchKernelGGL(ode_tsit5_kernel, dim3(64), dim3(256), 0, stream,
                     ts, y0, us, W1, b1, W2, b2, out);
}

// Round 9
// 1896.674 us; speedup vs baseline: 1.4612x; 1.1982x over previous
//
#include <hip/hip_runtime.h>

namespace {

typedef _Float16 h2 __attribute__((ext_vector_type(2)));

constexpr int KSTEPS = 512;
constexpr int NSTATE = 128;
constexpr int NINPUT = 32;
constexpr int HID    = 256;
constexpr int FANIN  = 161;
constexpr int BATCH  = 64;

// ---- workspace layout (bytes) ----
constexpr size_t WS_M  = 0;                                   // 256x256 f16 (M = W1y*W2)
constexpr size_t WS_C  = WS_M + (size_t)HID * HID * 2;        // 256 f32    (c = W1y*b2)
constexpr size_t WS_US = WS_C + HID * 4;                      // B*K*32 f16 (us transcoded)
constexpr size_t WS_HB = WS_US + (size_t)BATCH * KSTEPS * NINPUT * 2;  // B*K*256 f16
// total = WS_HB + 64*512*256*2 = ~18.2 MB

__device__ __forceinline__ float fdot2(h2 a, h2 b, float c) {
#if __has_builtin(__builtin_amdgcn_fdot2)
  return __builtin_amdgcn_fdot2(a, b, c, false);
#else
  return c + (float)a[0] * (float)b[0] + (float)a[1] * (float)b[1];
#endif
}

__device__ __forceinline__ float fast_tanh(float x) {
  float e2 = __expf(2.0f * x);
  return 1.0f - 2.0f / (e2 + 1.0f);
}

template <int CTRL>
__device__ __forceinline__ float dpp_add(float x) {
  int y = __builtin_amdgcn_update_dpp(0, __float_as_int(x), CTRL, 0xF, 0xF, false);
  return x + __int_as_float(y);
}
__device__ __forceinline__ float red8(float x) {
  x = dpp_add<0xB1>(x);    // xor 1
  x = dpp_add<0x4E>(x);    // xor 2
  x = dpp_add<0x141>(x);   // half-row mirror
  return x;
}

#define BAR() __asm__ volatile("s_waitcnt lgkmcnt(0)\n\ts_barrier" ::: "memory")

union F4 { float4 f; h2 h[4]; };

// ---------- K1: M = W1y*W2 (f16), c = W1y*b2 (f32) ----------
__global__ __launch_bounds__(256)
void k1_compose(const float* __restrict__ W1, const float* __restrict__ W2,
                const float* __restrict__ b2, _Float16* __restrict__ wsM,
                float* __restrict__ wsC) {
  const int j  = blockIdx.x;     // hidden row 0..255
  const int hc = threadIdx.x;    // hidden col 0..255
  const float* w1row = W1 + (size_t)j * FANIN + 1;   // y columns
  float acc = 0.0f;
  for (int o = 0; o < NSTATE; ++o)
    acc = __builtin_fmaf(w1row[o], W2[(size_t)o * HID + hc], acc);
  wsM[(size_t)j * HID + hc] = (_Float16)acc;
  if (hc == 0) {
    float ca = 0.0f;
    for (int o = 0; o < NSTATE; ++o) ca = __builtin_fmaf(w1row[o], b2[o], ca);
    wsC[j] = ca;
  }
}

// ---------- K1b: transcode us (f32 -> f16) ----------
__global__ __launch_bounds__(256)
void k1b_transcode(const float* __restrict__ us, _Float16* __restrict__ us16) {
  const size_t idx = ((size_t)blockIdx.x * 256 + threadIdx.x) * 4;
  const float4 v = *(const float4*)(us + idx);
  us16[idx + 0] = (_Float16)v.x;
  us16[idx + 1] = (_Float16)v.y;
  us16[idx + 2] = (_Float16)v.z;
  us16[idx + 3] = (_Float16)v.w;
}

// ---------- K2: sequential recurrence in hidden pre-activation space ----------
// 64 blocks x 256 threads (1 traj/block). Lane lt owns hidden row j = lt.
// Per phase (one per Tsit5 stage): read h_e (LDS), a_e = M.h_e + c (dot2 + red8),
// owner combines pre_{e+1} in fp32, tanh, writes h_{e+1}. ONE barrier per phase.
// hB = sum_e B_e h_e is stored to ws per step; y is reconstructed by K4.
__global__ __launch_bounds__(256, 1)
void k2_main(const float* __restrict__ ts,
             const float* __restrict__ y0,
             const float* __restrict__ W1,
             const float* __restrict__ b1,
             char* __restrict__ ws)
{
  const int lt = threadIdx.x;          // 0..255 == owned hidden row
  const int g  = lt >> 3;              // 0..31
  const int kc = lt & 7;               // 0..7
  const int b  = blockIdx.x;

  const _Float16* wsM  = (const _Float16*)(ws + WS_M);
  const float*    wsC  = (const float*)(ws + WS_C);
  const _Float16* us16 = (const _Float16*)(ws + WS_US) + (size_t)b * KSTEPS * NINPUT;
  _Float16*       wsHB = (_Float16*)(ws + WS_HB) + (size_t)b * KSTEPS * HID;

  // h double buffer: 8 chunks of 32 f16, stride 40 (80 B: banks 20kc%32 all distinct)
  __shared__ __align__(16) _Float16 hbuf[2][320];
  __shared__ __align__(16) float y0s[NSTATE];

  // ---- M chunk into registers: rows 8g..8g+7 x cols 32kc..32kc+31 ----
  h2 w1m[8][16];
  #pragma unroll
  for (int r = 0; r < 8; ++r) {
    const F4* mp = (const F4*)(wsM + (size_t)(8 * g + r) * HID + 32 * kc);
    F4 m0 = mp[0], m1 = mp[1], m2 = mp[2], m3 = mp[3];
    #pragma unroll
    for (int i = 0; i < 4; ++i) {
      w1m[r][i]      = m0.h[i];
      w1m[r][4 + i]  = m1.h[i];
      w1m[r][8 + i]  = m2.h[i];
      w1m[r][12 + i] = m3.h[i];
    }
  }
  // ---- per-owner-row constants ----
  const float* w1row = W1 + (size_t)lt * FANIN;
  const float  w1t   = w1row[0];
  h2 w1u[16];
  #pragma unroll
  for (int i = 0; i < 16; ++i)
    w1u[i] = h2{(_Float16)w1row[129 + 2 * i], (_Float16)w1row[130 + 2 * i]};
  const float cR = wsC[lt];

  // ---- P = W1y*y0 + b1 (fp32) ----
  if (lt < NSTATE) y0s[lt] = y0[(size_t)b * NSTATE + lt];
  __syncthreads();
  float P = b1[lt];
  {
    const float* wy = w1row + 1;
    #pragma unroll 8
    for (int o = 0; o < NSTATE; ++o) P = __builtin_fmaf(wy[o], y0s[o], P);
  }

  // Tsit5 tableau (b7=0). CcD[e] = abscissa of stage e+1.
  constexpr double CcD[5] = {0.161, 0.327, 0.9, 0.9800255409045097, 1.0};
  constexpr float Af[5][5] = {
    {0.161f, 0.f, 0.f, 0.f, 0.f},
    {-0.008480655492356989f, 0.335480655492357f, 0.f, 0.f, 0.f},
    {2.8971530571054935f, -6.359448489975075f, 4.3622954328695815f, 0.f, 0.f},
    {5.325864828439257f, -11.748883564062828f, 7.4955393428898365f, -0.09249506636175525f, 0.f},
    {5.86145544294642f, -12.92096931784711f, 8.159367898576159f, -0.071584973281401f,
     -0.028269050394068383f}};
  constexpr float Bf[6] = {0.09646076681806523f, 0.01f, 0.4798896504144996f,
                           1.379008574103742f, -3.290069515436081f, 2.324710524099774f};

  // ---- init: Ua = W1u*u_0; h_0; hB ----
  float Ua, Ub = 0.0f, Uaprev = 0.0f, D = 0.0f;
  {
    const F4* up = (const F4*)(us16);     // u_0, broadcast
    F4 u0 = up[0], u1 = up[1], u2 = up[2], u3 = up[3];
    float s = 0.0f;
    #pragma unroll
    for (int i = 0; i < 4; ++i) {
      s = fdot2(w1u[i], u0.h[i], s);
      s = fdot2(w1u[4 + i], u1.h[i], s);
      s = fdot2(w1u[8 + i], u2.h[i], s);
      s = fdot2(w1u[12 + i], u3.h[i], s);
    }
    Ua = s;
  }
  float tcur = ts[0], tn1 = ts[1];
  float dtp = 1.0f;
  const int slot = 40 * (lt >> 5) + (lt & 31);
  float h0v = fast_tanh(P + Ua + w1t * tcur);
  hbuf[0][slot] = (_Float16)h0v;
  float hB = Bf[0] * h0v;
  float aR[6];

  for (int i = 0; i < KSTEPS - 1; ++i) {
    const float dt = tn1 - tcur;
    const int   i2 = (i + 2 < KSTEPS) ? (i + 2) : (KSTEPS - 1);
    const float tn2 = ts[i2];

    #pragma unroll
    for (int e = 0; e < 6; ++e) {
      BAR();   // h_e ready in hbuf[e&1]

      // read h chunk (4x b128, conflict-free)
      const F4* hp = (const F4*)(&hbuf[e & 1][40 * kc]);
      F4 hc0 = hp[0], hc1 = hp[1], hc2 = hp[2], hc3 = hp[3];

      if (e == 5) {
        // hB complete (B0..B5 accumulated) -> fire-and-forget store
        wsHB[(size_t)i * HID + lt] = (_Float16)hB;
      }
      if (e == 0) {
        // Ub = W1u * u_{i+1}; D for this step
        const F4* up = (const F4*)(us16 + (size_t)(i + 1) * NINPUT);
        F4 u0 = up[0], u1 = up[1], u2 = up[2], u3 = up[3];
        float s = 0.0f;
        #pragma unroll
        for (int q = 0; q < 4; ++q) {
          s = fdot2(w1u[q], u0.h[q], s);
          s = fdot2(w1u[4 + q], u1.h[q], s);
          s = fdot2(w1u[8 + q], u2.h[q], s);
          s = fdot2(w1u[12 + q], u3.h[q], s);
        }
        Ub = s;
        D = (i == 0) ? (Ub - Ua) : (Ua - Uaprev) * (dt / dtp);
      }

      // ---- a_e = M*h_e + c : 8 rows x 16 dot2, 2 chains ----
      float acc[8];
      #pragma unroll
      for (int r = 0; r < 8; ++r) {
        float a0 = fdot2(w1m[r][0], hc0.h[0], 0.0f);
        float a1 = fdot2(w1m[r][1], hc0.h[1], 0.0f);
        a0 = fdot2(w1m[r][2],  hc0.h[2], a0);
        a1 = fdot2(w1m[r][3],  hc0.h[3], a1);
        a0 = fdot2(w1m[r][4],  hc1.h[0], a0);
        a1 = fdot2(w1m[r][5],  hc1.h[1], a1);
        a0 = fdot2(w1m[r][6],  hc1.h[2], a0);
        a1 = fdot2(w1m[r][7],  hc1.h[3], a1);
        a0 = fdot2(w1m[r][8],  hc2.h[0], a0);
        a1 = fdot2(w1m[r][9],  hc2.h[1], a1);
        a0 = fdot2(w1m[r][10], hc2.h[2], a0);
        a1 = fdot2(w1m[r][11], hc2.h[3], a1);
        a0 = fdot2(w1m[r][12], hc3.h[0], a0);
        a1 = fdot2(w1m[r][13], hc3.h[1], a1);
        a0 = fdot2(w1m[r][14], hc3.h[2], a0);
        a1 = fdot2(w1m[r][15], hc3.h[3], a1);
        acc[r] = a0 + a1;
      }
      #pragma unroll
      for (int r = 0; r < 8; ++r) acc[r] = red8(acc[r]);
      float ae = acc[0];
      #pragma unroll
      for (int r = 1; r < 8; ++r) ae = (kc == r) ? acc[r] : ae;
      ae += cR;          // a_e[lt] for every lane (owner row = lt)
      aR[e] = ae;

      if (e < 5) {
        // pre_{e+1} = P + dt*sum(A[e][m]*a_m) + u-term + t-term (all fp32)
        float acm = 0.0f;
        #pragma unroll
        for (int mm = 0; mm <= e; ++mm) acm = __builtin_fmaf(Af[e][mm], aR[mm], acm);
        const double th = CcD[e];
        const float cu0 = (float)(th * th * th - 2.0 * th * th + 1.0);
        const float cu1 = (float)(2.0 * th * th - th * th * th);
        const float cd0 = (float)(th * th * th - 2.0 * th * th + th);
        const float ut  = cu0 * Ua + cu1 * Ub + cd0 * D;
        const float te  = __builtin_fmaf((float)th, dt, tcur);
        float pre = __builtin_fmaf(dt, acm, P) + ut;
        pre = __builtin_fmaf(w1t, te, pre);
        const float hv = fast_tanh(pre);
        hbuf[(e + 1) & 1][slot] = (_Float16)hv;
        hB = __builtin_fmaf(Bf[e + 1], hv, hB);
      } else {
        // P update, then h_0 for next step
        float acm = 0.0f;
        #pragma unroll
        for (int mm = 0; mm < 6; ++mm) acm = __builtin_fmaf(Bf[mm], aR[mm], acm);
        P = __builtin_fmaf(dt, acm, P);
        float pre = P + Ub;                       // u(theta=0) of next step = u_{i+1}
        pre = __builtin_fmaf(w1t, tn1, pre);
        const float hv = fast_tanh(pre);
        hbuf[0][slot] = (_Float16)hv;
        hB = Bf[0] * hv;
      }
    }

    // roll step state
    Uaprev = Ua; Ua = Ub;
    dtp = dt; tcur = tn1; tn1 = tn2;
  }
}

// ---------- K4: out[b][i+1] = y0 + W2 * S_i,  S_i = sum_{i'<=i} dt*hB ----------
// 64 blocks x 256 thr. Thread lt owns S[lt] (fp32). Matvec: o = lt>>1, half = lt&1.
__global__ __launch_bounds__(256, 1)
void k4_out(const float* __restrict__ ts,
            const float* __restrict__ y0,
            const float* __restrict__ W2,
            const char* __restrict__ ws,
            float* __restrict__ out)
{
  const int lt = threadIdx.x;
  const int b  = blockIdx.x;
  const int o    = lt >> 1;
  const int half = lt & 1;

  const _Float16* wsHB = (const _Float16*)(ws + WS_HB) + (size_t)b * KSTEPS * HID;
  float* outb = out + (size_t)b * KSTEPS * NSTATE;

  __shared__ __align__(16) _Float16 Sb[HID];

  // W2 half-row into f16 registers
  h2 w2r[64];
  {
    const float* row = W2 + (size_t)o * HID + 128 * half;
    #pragma unroll
    for (int i = 0; i < 64; ++i)
      w2r[i] = h2{(_Float16)row[2 * i], (_Float16)row[2 * i + 1]};
  }
  const float y0o = y0[(size_t)b * NSTATE + o];
  if (lt < NSTATE) outb[lt] = y0[(size_t)b * NSTATE + lt];   // row 0 = y0

  float S = 0.0f;
  float tc = ts[0], tn = ts[1];
  float hcur = (float)wsHB[lt];                 // hB[0]
  for (int i = 0; i < KSTEPS - 1; ++i) {
    // prefetch next
    const int in = (i + 1 < KSTEPS - 1) ? (i + 1) : (KSTEPS - 2);
    const float hnext = (float)wsHB[(size_t)in * HID + lt];
    const float tnn = ts[(i + 2 < KSTEPS) ? (i + 2) : (KSTEPS - 1)];

    const float dt = tn - tc;
    S = __builtin_fmaf(dt, hcur, S);
    Sb[lt] = (_Float16)S;
    __syncthreads();

    const F4* sp = (const F4*)(&Sb[128 * half]);
    float v0 = 0.0f, v1 = 0.0f;
    #pragma unroll
    for (int q = 0; q < 16; ++q) {
      F4 sc = sp[q];
      v0 = fdot2(w2r[4 * q + 0], sc.h[0], v0);
      v1 = fdot2(w2r[4 * q + 1], sc.h[1], v1);
      v0 = fdot2(w2r[4 * q + 2], sc.h[2], v0);
      v1 = fdot2(w2r[4 * q + 3], sc.h[3], v1);
    }
    float v = v0 + v1;
    v += __shfl_xor(v, 1);
    if (half == 0) outb[(size_t)(i + 1) * NSTATE + o] = y0o + v;
    __syncthreads();   // protect Sb rewrite

    hcur = hnext; tc = tn; tn = tnn;
  }
}

} // namespace

extern "C" void kernel_launch(void* const* d_in, const int* in_sizes, int n_in,
                              void* d_out, int out_size, void* d_ws, size_t ws_size,
                              hipStream_t stream) {
  const float* ts = (const float*)d_in[0];
  const float* y0 = (const float*)d_in[1];
  const float* us = (const float*)d_in[2];
  const float* W1 = (const float*)d_in[3];
  const float* b1 = (const float*)d_in[4];
  const float* W2 = (const float*)d_in[5];
  const float* b2 = (const float*)d_in[6];
  float* out = (float*)d_out;
  char* ws = (char*)d_ws;

  _Float16* wsM  = (_Float16*)(ws + WS_M);
  float*    wsC  = (float*)(ws + WS_C);
  _Float16* us16 = (_Float16*)(ws + WS_US);

  hipLaunchKernelGGL(k1_compose, dim3(HID), dim3(HID), 0, stream, W1, W2, b2, wsM, wsC);
  hipLaunchKernelGGL(k1b_transcode, dim3(BATCH * KSTEPS * NINPUT / 1024), dim3(256),
                     0, stream, us, us16);
  hipLaunchKernelGGL(k2_main, dim3(BATCH), dim3(256), 0, stream, ts, y0, W1, b1, ws);
  hipLaunchKernelGGL(k4_out, dim3(BATCH), dim3(256), 0, stream, ts, y0, W2,
                     (const char*)ws, out);
}